// Round 6
// baseline (263.969 us; speedup 1.0000x reference)
//
#include <hip/hip_runtime.h>
#include <hip/hip_bf16.h>
#include <math.h>

typedef __bf16 bf16_t;
typedef bf16_t bf16x8 __attribute__((ext_vector_type(8)));
typedef float f32x4 __attribute__((ext_vector_type(4)));
typedef unsigned short u16x8 __attribute__((ext_vector_type(8)));

// ---------------- async global->LDS (16B per lane) ----------------
__device__ __forceinline__ void g2l16(const bf16_t* g, bf16_t* l) {
    __builtin_amdgcn_global_load_lds(
        (const __attribute__((address_space(1))) void*)g,
        (__attribute__((address_space(3))) void*)l, 16, 0, 0);
}

// ---------------- prep v2: region-partitioned, branch-hoisted, unrolled -------
__global__ void prep_all(const void* __restrict__ x,
                         const void* __restrict__ cb1, const int* __restrict__ idx1,
                         const void* __restrict__ b1,
                         const void* __restrict__ cb2, const int* __restrict__ idx2,
                         const void* __restrict__ b2,
                         bf16_t* __restrict__ xb, bf16_t* __restrict__ w1b,
                         bf16_t* __restrict__ w2b, float* __restrict__ b1f,
                         float* __restrict__ b2f, int* __restrict__ flag, int M) {
    __shared__ int s_bad;
    const int t = threadIdx.x;
    if (t == 0) s_bad = 0;
    __syncthreads();
    {
        u16x8 v = ((const u16x8*)x)[t];
        int cnt = 0;
#pragma unroll
        for (int j = 0; j < 8; ++j) cnt += (((v[j] >> 7) & 0xFF) >= 0x88);
#pragma unroll
        for (int o = 32; o > 0; o >>= 1) cnt += __shfl_down(cnt, o, 64);
        if ((t & 63) == 0) atomicAdd(&s_bad, cnt);
    }
    __syncthreads();
    const int f32 = (s_bad > 4);
    if (blockIdx.x == 0 && t == 0) flag[0] = f32;

    const int bX = M >> 3;
    const int b = blockIdx.x;

    if (b < bX) {
        const int c0 = b * 1024 + t;
        if (f32) {
            const float4* p = (const float4*)x;
#pragma unroll
            for (int k = 0; k < 4; ++k) {
                const int ci = c0 + k * 256;
                float4 a = p[2 * ci], bb = p[2 * ci + 1];
                bf16x8 o;
                o[0] = (bf16_t)a.x;  o[1] = (bf16_t)a.y;
                o[2] = (bf16_t)a.z;  o[3] = (bf16_t)a.w;
                o[4] = (bf16_t)bb.x; o[5] = (bf16_t)bb.y;
                o[6] = (bf16_t)bb.z; o[7] = (bf16_t)bb.w;
                *(bf16x8*)(xb + (size_t)ci * 8) = o;
            }
        } else {
            const bf16x8* p = (const bf16x8*)x;
#pragma unroll
            for (int k = 0; k < 4; ++k) {
                const int ci = c0 + k * 256;
                *(bf16x8*)(xb + (size_t)ci * 8) = p[ci];
            }
        }
        return;
    }

    int wb = b - bX;
    if (wb < 512) {
        const int c0 = wb * 1024 + t;
        if (f32) {
#pragma unroll
            for (int k = 0; k < 4; ++k) {
                const int ii = c0 + k * 256;
                const int r = ii >> 7;
                const int col = (ii & 127) << 3;
                const int cc = col >> 7;
                const int code = idx1[cc * 4096 + r];
                const float* s = (const float*)cb1 + (size_t)(cc * 256 + code) * 128 + (col & 127);
                float4 a = *(const float4*)s, bb = *(const float4*)(s + 4);
                bf16x8 o;
                o[0] = (bf16_t)a.x;  o[1] = (bf16_t)a.y;
                o[2] = (bf16_t)a.z;  o[3] = (bf16_t)a.w;
                o[4] = (bf16_t)bb.x; o[5] = (bf16_t)bb.y;
                o[6] = (bf16_t)bb.z; o[7] = (bf16_t)bb.w;
                *(bf16x8*)(w1b + (size_t)r * 1024 + col) = o;
            }
        } else {
#pragma unroll
            for (int k = 0; k < 4; ++k) {
                const int ii = c0 + k * 256;
                const int r = ii >> 7;
                const int col = (ii & 127) << 3;
                const int cc = col >> 7;
                const int code = idx1[cc * 4096 + r];
                *(bf16x8*)(w1b + (size_t)r * 1024 + col) =
                    *(const bf16x8*)((const bf16_t*)cb1 + (size_t)(cc * 256 + code) * 128 + (col & 127));
            }
        }
        return;
    }

    wb -= 512;
    {
        const int c0 = wb * 1024 + t;
        if (f32) {
#pragma unroll
            for (int k = 0; k < 4; ++k) {
                const int ii = c0 + k * 256;
                const int r = ii >> 9;
                const int col = (ii & 511) << 3;
                const int cc = col >> 9;
                const int code = idx2[cc * 1024 + r];
                const float* s = (const float*)cb2 + (size_t)(cc * 256 + code) * 512 + (col & 511);
                float4 a = *(const float4*)s, bb = *(const float4*)(s + 4);
                bf16x8 o;
                o[0] = (bf16_t)a.x;  o[1] = (bf16_t)a.y;
                o[2] = (bf16_t)a.z;  o[3] = (bf16_t)a.w;
                o[4] = (bf16_t)bb.x; o[5] = (bf16_t)bb.y;
                o[6] = (bf16_t)bb.z; o[7] = (bf16_t)bb.w;
                *(bf16x8*)(w2b + (size_t)r * 4096 + col) = o;
            }
        } else {
#pragma unroll
            for (int k = 0; k < 4; ++k) {
                const int ii = c0 + k * 256;
                const int r = ii >> 9;
                const int col = (ii & 511) << 3;
                const int cc = col >> 9;
                const int code = idx2[cc * 1024 + r];
                *(bf16x8*)(w2b + (size_t)r * 4096 + col) =
                    *(const bf16x8*)((const bf16_t*)cb2 + (size_t)(cc * 256 + code) * 512 + (col & 511));
            }
        }
    }

    if (wb == 511) {
        for (int g = t; g < 640; g += 256) {
#pragma unroll
            for (int j = 0; j < 8; ++j) {
                const int e = g * 8 + j;
                const void* src = (e < 4096) ? b1 : b2;
                const int k = (e < 4096) ? e : e - 4096;
                const float v = f32 ? ((const float*)src)[k]
                                    : (float)(((const bf16_t*)src)[k]);
                if (e < 4096) b1f[k] = v; else b2f[k] = v;
            }
        }
    }
}

// ---------------- GEMM 128^2 (proven; GEMM2 + in-run control) ----------------
template <bool XCDSW, bool GELU, bool DYNOUT>
__global__ __launch_bounds__(256, 2)
void gemm_bt(const bf16_t* __restrict__ A, const bf16_t* __restrict__ Bw,
             const float* __restrict__ bias,
             bf16_t* __restrict__ obf, float* __restrict__ of32,
             int M, int N, int K, const int* __restrict__ flag) {
    __shared__ __attribute__((aligned(16))) bf16_t sA[128 * 64];
    __shared__ __attribute__((aligned(16))) bf16_t sB[128 * 64];

    const int tid = threadIdx.x;

    int bm, bn;
    if (XCDSW) {
        const int l = blockIdx.y * gridDim.x + blockIdx.x;
        const int xcd = l & 7;
        const int i = l >> 3;
        const int per = gridDim.y >> 3;
        bm = (xcd * per + (i % per)) << 7;
        bn = (i / per) << 7;
    } else {
        bm = blockIdx.y << 7;
        bn = blockIdx.x << 7;
    }

    const int row0 = tid >> 3;
    const int kc0 = ((tid & 7) - row0) & 7;
    const bf16_t* gA = A + (size_t)(bm + row0) * K + kc0 * 8;
    const bf16_t* gB = Bw + (size_t)(bn + row0) * K + kc0 * 8;
    bf16_t* lA = sA + tid * 8;
    bf16_t* lB = sB + tid * 8;
    const size_t pskip = (size_t)32 * K;

    const int lane = tid & 63;
    const int wave = tid >> 6;
    const int quad = lane >> 4;
    const int lr = lane & 15;
    const int wm = (wave & 1) << 6;
    const int wn = (wave >> 1) << 6;

    const int arow = wm + lr;
    const int brow = wn + lr;
    const bf16x8* pA0 = (const bf16x8*)(sA + arow * 64 + ((quad + arow) & 7) * 8);
    const bf16x8* pA1 = (const bf16x8*)(sA + arow * 64 + ((quad + 4 + arow) & 7) * 8);
    const bf16x8* pB0 = (const bf16x8*)(sB + brow * 64 + ((quad + brow) & 7) * 8);
    const bf16x8* pB1 = (const bf16x8*)(sB + brow * 64 + ((quad + 4 + brow) & 7) * 8);

    f32x4 acc[4][4] = {};

    for (int k0 = 0; k0 < K; k0 += 64) {
#pragma unroll
        for (int p = 0; p < 4; ++p) g2l16(gA + p * pskip + k0, lA + p * 2048);
#pragma unroll
        for (int p = 0; p < 4; ++p) g2l16(gB + p * pskip + k0, lB + p * 2048);
        __syncthreads();

        bf16x8 af[4], bf[4];
#pragma unroll
        for (int f = 0; f < 4; ++f) { af[f] = pA0[f * 128]; bf[f] = pB0[f * 128]; }
#pragma unroll
        for (int mi = 0; mi < 4; ++mi)
#pragma unroll
            for (int ni = 0; ni < 4; ++ni)
                acc[mi][ni] = __builtin_amdgcn_mfma_f32_16x16x32_bf16(
                    af[mi], bf[ni], acc[mi][ni], 0, 0, 0);
#pragma unroll
        for (int f = 0; f < 4; ++f) { af[f] = pA1[f * 128]; bf[f] = pB1[f * 128]; }
#pragma unroll
        for (int mi = 0; mi < 4; ++mi)
#pragma unroll
            for (int ni = 0; ni < 4; ++ni)
                acc[mi][ni] = __builtin_amdgcn_mfma_f32_16x16x32_bf16(
                    af[mi], bf[ni], acc[mi][ni], 0, 0, 0);
        __syncthreads();
    }

    const int outf32 = DYNOUT ? *flag : 0;
#pragma unroll
    for (int mi = 0; mi < 4; ++mi) {
#pragma unroll
        for (int ni = 0; ni < 4; ++ni) {
            const int n = bn + wn + ni * 16 + lr;
            const float bs = bias[n];
            f32x4 v = acc[mi][ni];
#pragma unroll
            for (int r = 0; r < 4; ++r) {
                const int m = bm + wm + mi * 16 + quad * 4 + r;
                float val = v[r] + bs;
                if (GELU) val = 0.5f * val * (1.0f + erff(val * 0.70710678118654752f));
                const size_t o = (size_t)m * N + n;
                if (DYNOUT) {
                    if (outf32) of32[o] = val;
                    else        obf[o] = (bf16_t)val;
                } else {
                    obf[o] = (bf16_t)val;
                }
            }
        }
    }
}

// ---------------- GEMM 256^2 v4: race-fixed counted-vmcnt schedule ------------
// v3's absmax fail root cause: stages into current-buffer halves whose rows
// were still due to be read (wave banding: wm=0 reads rows 0..127 at p1 AND
// p2; wn=0,1 read Blo rows at p1 AND p3). v4 hazard-correct derivation:
//   A halves last ds_read @p2 (afh), B halves last ds_read @p3 (b23).
//   Hold afl (p1->p4) and afh (p2->p3) in registers -> NO re-reads (R2's
//   proven-correct discipline, register profile identical to R2's fit).
//   Stage cadence: t+1.Bhi@p1 (other buf; last read (t-1).p3),
//                  t+2.Alo@p3, t+2.Ahi+t+2.Blo@p4 (cur buf, halves free).
//   Every stage issues >= 1 full barrier after its slot's last read.
//   Ledger: vmcnt(6) once per tile at p4-end retires exactly tile t+1
//   (newest retired = t+1.Bhi issued @t.p1 -> 3 phases of lead), leaves
//   {t+2.Alo, t+2.Ahi, t+2.Blo} in flight. Reads/phase: 12/8/4/0.
template <bool GELU, bool DYNOUT>
__global__ __launch_bounds__(512, 2)
void gemm256(const bf16_t* __restrict__ A, const bf16_t* __restrict__ Bw,
             const float* __restrict__ bias,
             bf16_t* __restrict__ obf, float* __restrict__ of32,
             int M, int N, int K, const int* __restrict__ flag) {
    __shared__ __attribute__((aligned(16))) bf16_t sA[2 * 256 * 64];
    __shared__ __attribute__((aligned(16))) bf16_t sB[2 * 256 * 64];

    const int tid = threadIdx.x;
    const int NT = K >> 6;

    // XCD-banded bijective swizzle (grid % 8 == 0)
    const int l = blockIdx.x;
    const int nbm = M >> 8;
    const int per = nbm >> 3;
    const int xcd = l & 7;
    const int i = l >> 3;
    const int bm = (xcd * per + (i % per)) << 8;
    const int bn = (i / per) << 8;

    const int row0 = tid >> 3;                    // 0..63
    const int kc = ((tid & 7) - row0) & 7;
    const bf16_t* gA0 = A + (size_t)(bm + row0) * K + kc * 8;
    const bf16_t* gB0 = Bw + (size_t)(bn + row0) * K + kc * 8;
    bf16_t* lA0 = sA + tid * 8;
    bf16_t* lB0 = sB + tid * 8;

#define STAGE_A(off_, h_, kt_) do {                                   \
    const bf16_t* g_ = gA0 + (size_t)((h_) * 128) * K + (kt_) * 64;   \
    bf16_t* l_ = lA0 + (off_) + (h_) * 8192;                          \
    g2l16(g_, l_);                                                    \
    g2l16(g_ + (size_t)64 * K, l_ + 4096);                            \
} while (0)
#define STAGE_B(off_, h_, kt_) do {                                   \
    const bf16_t* g_ = gB0 + (size_t)((h_) * 128) * K + (kt_) * 64;   \
    bf16_t* l_ = lB0 + (off_) + (h_) * 8192;                          \
    g2l16(g_, l_);                                                    \
    g2l16(g_ + (size_t)64 * K, l_ + 4096);                            \
} while (0)

    const int lane = tid & 63;
    const int wave = tid >> 6;
    const int wm = wave >> 2;          // 0..1
    const int wn = wave & 3;           // 0..3
    const int lr = lane & 15;
    const int quad = lane >> 4;
    const int c0 = ((quad + lr) & 7) * 8;
    const int c1 = ((quad + lr + 4) & 7) * 8;
    const bf16_t* pA = sA + (wm * 128 + lr) * 64;
    const bf16_t* pB = sB + (wn * 64 + lr) * 64;

    f32x4 acc[8][4] = {};
    bf16x8 afl[4][2], afh[4][2], bfr[2][2];

    // prologue: tile0 fully (8 loads), then {1.Alo, 1.Ahi, 1.Blo} (6 loads);
    // vmcnt(6) retires tile0, leaves the 6 -- the steady-state carry.
    STAGE_A(0, 0, 0); STAGE_A(0, 1, 0); STAGE_B(0, 0, 0); STAGE_B(0, 1, 0);
    if (NT > 1) { STAGE_A(16384, 0, 1); STAGE_A(16384, 1, 1); STAGE_B(16384, 0, 1); }
    asm volatile("s_waitcnt vmcnt(6)" ::: "memory");
    __builtin_amdgcn_s_barrier();

    for (int t = 0; t < NT; ++t) {
        const int bo = (t & 1) << 14;       // this tile's buffer (elements)
        const int obo = bo ^ 16384;         // other buffer (tile t+1)

        // ---- p1: Q(0,0) — read afl(8) + b01(4); stage t+1.Bhi (other buf)
#pragma unroll
        for (int mi = 0; mi < 4; ++mi) {
            afl[mi][0] = *(const bf16x8*)(pA + bo + mi * 1024 + c0);
            afl[mi][1] = *(const bf16x8*)(pA + bo + mi * 1024 + c1);
        }
#pragma unroll
        for (int j = 0; j < 2; ++j) {
            bfr[j][0] = *(const bf16x8*)(pB + bo + j * 1024 + c0);
            bfr[j][1] = *(const bf16x8*)(pB + bo + j * 1024 + c1);
        }
        if (t + 1 < NT) STAGE_B(obo, 1, t + 1);
        __builtin_amdgcn_s_barrier();
        asm volatile("s_waitcnt lgkmcnt(0)" ::: "memory");
        __builtin_amdgcn_s_setprio(1);
#pragma unroll
        for (int mi = 0; mi < 4; ++mi)
#pragma unroll
            for (int j = 0; j < 2; ++j) {
                acc[mi][j] = __builtin_amdgcn_mfma_f32_16x16x32_bf16(
                    afl[mi][0], bfr[j][0], acc[mi][j], 0, 0, 0);
                acc[mi][j] = __builtin_amdgcn_mfma_f32_16x16x32_bf16(
                    afl[mi][1], bfr[j][1], acc[mi][j], 0, 0, 0);
            }
        __builtin_amdgcn_s_setprio(0);
        __builtin_amdgcn_s_barrier();

        // ---- p2: Q(1,0) — read afh(8), reuse b01 (no staging)
#pragma unroll
        for (int mi = 0; mi < 4; ++mi) {
            afh[mi][0] = *(const bf16x8*)(pA + bo + (4 + mi) * 1024 + c0);
            afh[mi][1] = *(const bf16x8*)(pA + bo + (4 + mi) * 1024 + c1);
        }
        __builtin_amdgcn_s_barrier();
        asm volatile("s_waitcnt lgkmcnt(0)" ::: "memory");
        __builtin_amdgcn_s_setprio(1);
#pragma unroll
        for (int mi = 0; mi < 4; ++mi)
#pragma unroll
            for (int j = 0; j < 2; ++j) {
                acc[4 + mi][j] = __builtin_amdgcn_mfma_f32_16x16x32_bf16(
                    afh[mi][0], bfr[j][0], acc[4 + mi][j], 0, 0, 0);
                acc[4 + mi][j] = __builtin_amdgcn_mfma_f32_16x16x32_bf16(
                    afh[mi][1], bfr[j][1], acc[4 + mi][j], 0, 0, 0);
            }
        __builtin_amdgcn_s_setprio(0);
        __builtin_amdgcn_s_barrier();

        // ---- p3: Q(1,1) — read b23(4) (overwrite bfr), reuse afh;
        //                   stage t+2.Alo (cur buf Alo: last read @p2)
#pragma unroll
        for (int j = 0; j < 2; ++j) {
            bfr[j][0] = *(const bf16x8*)(pB + bo + (2 + j) * 1024 + c0);
            bfr[j][1] = *(const bf16x8*)(pB + bo + (2 + j) * 1024 + c1);
        }
        if (t + 2 < NT) STAGE_A(bo, 0, t + 2);
        __builtin_amdgcn_s_barrier();
        asm volatile("s_waitcnt lgkmcnt(0)" ::: "memory");
        __builtin_amdgcn_s_setprio(1);
#pragma unroll
        for (int mi = 0; mi < 4; ++mi)
#pragma unroll
            for (int j = 0; j < 2; ++j) {
                acc[4 + mi][2 + j] = __builtin_amdgcn_mfma_f32_16x16x32_bf16(
                    afh[mi][0], bfr[j][0], acc[4 + mi][2 + j], 0, 0, 0);
                acc[4 + mi][2 + j] = __builtin_amdgcn_mfma_f32_16x16x32_bf16(
                    afh[mi][1], bfr[j][1], acc[4 + mi][2 + j], 0, 0, 0);
            }
        __builtin_amdgcn_s_setprio(0);
        __builtin_amdgcn_s_barrier();

        // ---- p4: Q(0,1) — no reads (afl held from p1, b23 held from p3);
        //          stage t+2.Ahi (last read @p2) + t+2.Blo (last read @p3)
        if (t + 2 < NT) { STAGE_A(bo, 1, t + 2); STAGE_B(bo, 0, t + 2); }
        __builtin_amdgcn_s_setprio(1);
#pragma unroll
        for (int mi = 0; mi < 4; ++mi)
#pragma unroll
            for (int j = 0; j < 2; ++j) {
                acc[mi][2 + j] = __builtin_amdgcn_mfma_f32_16x16x32_bf16(
                    afl[mi][0], bfr[j][0], acc[mi][2 + j], 0, 0, 0);
                acc[mi][2 + j] = __builtin_amdgcn_mfma_f32_16x16x32_bf16(
                    afl[mi][1], bfr[j][1], acc[mi][2 + j], 0, 0, 0);
            }
        __builtin_amdgcn_s_setprio(0);
        // counted wait: retire exactly tile t+1 (newest: t+1.Bhi @t.p1, 3-phase
        // lead); keep {t+2.Alo, t+2.Ahi, t+2.Blo} in flight. Tail: drain.
        if (t + 2 < NT)      asm volatile("s_waitcnt vmcnt(6)" ::: "memory");
        else if (t + 1 < NT) asm volatile("s_waitcnt vmcnt(0)" ::: "memory");
        __builtin_amdgcn_s_barrier();
    }

#undef STAGE_A
#undef STAGE_B

    const int outf32 = DYNOUT ? *flag : 0;
    const int mrow = bm + wm * 128 + quad * 4;
    const int ncol = bn + wn * 64 + lr;
#pragma unroll
    for (int mi = 0; mi < 8; ++mi) {
#pragma unroll
        for (int j = 0; j < 4; ++j) {
            const int n = ncol + j * 16;
            const float bs = bias[n];
            f32x4 v = acc[mi][j];
#pragma unroll
            for (int r = 0; r < 4; ++r) {
                const int m = mrow + mi * 16 + r;
                float val = v[r] + bs;
                if (GELU) val = 0.5f * val * (1.0f + erff(val * 0.70710678118654752f));
                const size_t o = (size_t)m * N + n;
                if (DYNOUT) {
                    if (outf32) of32[o] = val;
                    else        obf[o] = (bf16_t)val;
                } else {
                    obf[o] = (bf16_t)val;
                }
            }
        }
    }
}

// ---------------- launch ----------------
extern "C" void kernel_launch(void* const* d_in, const int* in_sizes, int n_in,
                              void* d_out, int out_size, void* d_ws, size_t ws_size,
                              hipStream_t stream) {
    const void* x   = d_in[0];
    const void* cb1 = d_in[1];
    const int*  idx1 = (const int*)d_in[2];
    const void* b1  = d_in[3];
    const void* cb2 = d_in[4];
    const int*  idx2 = (const int*)d_in[5];
    const void* b2  = d_in[6];

    const int D = 1024, H = 4096;
    const int M = in_sizes[0] / D;     // 8192

    char* ws = (char*)d_ws;
    bf16_t* xb  = (bf16_t*)ws;                                   // M*D bf16 (16 MB)
    bf16_t* w1b = (bf16_t*)(ws + (size_t)M * D * 2);             // H*D bf16 (8 MB)
    bf16_t* hb  = (bf16_t*)((char*)w1b + (size_t)H * D * 2);     // M*H bf16 (64 MB)
    bf16_t* w2b = (bf16_t*)((char*)hb + (size_t)M * H * 2);      // D*H bf16 (8 MB)
    float*  b1f = (float*)((char*)w2b + (size_t)D * H * 2);      // H f32
    float*  b2f = b1f + H;                                       // D f32
    int*    flag = (int*)(b2f + D);

    prep_all<<<(M >> 3) + 1024, 256, 0, stream>>>(x, cb1, idx1, b1, cb2, idx2, b2,
                                                  xb, w1b, w2b, b1f, b2f, flag, M);

    // GEMM1: 256^2 v4 (race-fixed counted-vmcnt). grid = 32*16 = 512
    gemm256<true, false><<<(M / 256) * (H / 256), 512, 0, stream>>>(
        xb, w1b, b1f, hb, nullptr, M, H, D, flag);

    // GEMM2: unchanged 128^2 (in-run control for clock normalization)
    dim3 g2(D / 128, M / 128);   // (8, 64)
    gemm_bt<true, false, true><<<g2, 256, 0, stream>>>(hb, w2b, b2f,
        (bf16_t*)d_out, (float*)d_out, M, D, H, flag);
}

// Round 7
// 246.193 us; speedup vs baseline: 1.0722x; 1.0722x over previous
//
#include <hip/hip_runtime.h>
#include <hip/hip_bf16.h>
#include <math.h>

typedef __bf16 bf16_t;
typedef bf16_t bf16x8 __attribute__((ext_vector_type(8)));
typedef float f32x4 __attribute__((ext_vector_type(4)));
typedef unsigned short u16x8 __attribute__((ext_vector_type(8)));

// ---------------- async global->LDS (16B per lane) ----------------
__device__ __forceinline__ void g2l16(const bf16_t* g, bf16_t* l) {
    __builtin_amdgcn_global_load_lds(
        (const __attribute__((address_space(1))) void*)g,
        (__attribute__((address_space(3))) void*)l, 16, 0, 0);
}

// ---------------- prep v2: region-partitioned, branch-hoisted, unrolled -------
// Proven R4/R6: absmax pass; ~35us (vs 75us for the grid-stride v1).
__global__ void prep_all(const void* __restrict__ x,
                         const void* __restrict__ cb1, const int* __restrict__ idx1,
                         const void* __restrict__ b1,
                         const void* __restrict__ cb2, const int* __restrict__ idx2,
                         const void* __restrict__ b2,
                         bf16_t* __restrict__ xb, bf16_t* __restrict__ w1b,
                         bf16_t* __restrict__ w2b, float* __restrict__ b1f,
                         float* __restrict__ b2f, int* __restrict__ flag, int M) {
    __shared__ int s_bad;
    const int t = threadIdx.x;
    if (t == 0) s_bad = 0;
    __syncthreads();
    {
        u16x8 v = ((const u16x8*)x)[t];
        int cnt = 0;
#pragma unroll
        for (int j = 0; j < 8; ++j) cnt += (((v[j] >> 7) & 0xFF) >= 0x88);
#pragma unroll
        for (int o = 32; o > 0; o >>= 1) cnt += __shfl_down(cnt, o, 64);
        if ((t & 63) == 0) atomicAdd(&s_bad, cnt);
    }
    __syncthreads();
    const int f32 = (s_bad > 4);
    if (blockIdx.x == 0 && t == 0) flag[0] = f32;

    const int bX = M >> 3;
    const int b = blockIdx.x;

    if (b < bX) {
        const int c0 = b * 1024 + t;
        if (f32) {
            const float4* p = (const float4*)x;
#pragma unroll
            for (int k = 0; k < 4; ++k) {
                const int ci = c0 + k * 256;
                float4 a = p[2 * ci], bb = p[2 * ci + 1];
                bf16x8 o;
                o[0] = (bf16_t)a.x;  o[1] = (bf16_t)a.y;
                o[2] = (bf16_t)a.z;  o[3] = (bf16_t)a.w;
                o[4] = (bf16_t)bb.x; o[5] = (bf16_t)bb.y;
                o[6] = (bf16_t)bb.z; o[7] = (bf16_t)bb.w;
                *(bf16x8*)(xb + (size_t)ci * 8) = o;
            }
        } else {
            const bf16x8* p = (const bf16x8*)x;
#pragma unroll
            for (int k = 0; k < 4; ++k) {
                const int ci = c0 + k * 256;
                *(bf16x8*)(xb + (size_t)ci * 8) = p[ci];
            }
        }
        return;
    }

    int wb = b - bX;
    if (wb < 512) {
        const int c0 = wb * 1024 + t;
        if (f32) {
#pragma unroll
            for (int k = 0; k < 4; ++k) {
                const int ii = c0 + k * 256;
                const int r = ii >> 7;
                const int col = (ii & 127) << 3;
                const int cc = col >> 7;
                const int code = idx1[cc * 4096 + r];
                const float* s = (const float*)cb1 + (size_t)(cc * 256 + code) * 128 + (col & 127);
                float4 a = *(const float4*)s, bb = *(const float4*)(s + 4);
                bf16x8 o;
                o[0] = (bf16_t)a.x;  o[1] = (bf16_t)a.y;
                o[2] = (bf16_t)a.z;  o[3] = (bf16_t)a.w;
                o[4] = (bf16_t)bb.x; o[5] = (bf16_t)bb.y;
                o[6] = (bf16_t)bb.z; o[7] = (bf16_t)bb.w;
                *(bf16x8*)(w1b + (size_t)r * 1024 + col) = o;
            }
        } else {
#pragma unroll
            for (int k = 0; k < 4; ++k) {
                const int ii = c0 + k * 256;
                const int r = ii >> 7;
                const int col = (ii & 127) << 3;
                const int cc = col >> 7;
                const int code = idx1[cc * 4096 + r];
                *(bf16x8*)(w1b + (size_t)r * 1024 + col) =
                    *(const bf16x8*)((const bf16_t*)cb1 + (size_t)(cc * 256 + code) * 128 + (col & 127));
            }
        }
        return;
    }

    wb -= 512;
    {
        const int c0 = wb * 1024 + t;
        if (f32) {
#pragma unroll
            for (int k = 0; k < 4; ++k) {
                const int ii = c0 + k * 256;
                const int r = ii >> 9;
                const int col = (ii & 511) << 3;
                const int cc = col >> 9;
                const int code = idx2[cc * 1024 + r];
                const float* s = (const float*)cb2 + (size_t)(cc * 256 + code) * 512 + (col & 511);
                float4 a = *(const float4*)s, bb = *(const float4*)(s + 4);
                bf16x8 o;
                o[0] = (bf16_t)a.x;  o[1] = (bf16_t)a.y;
                o[2] = (bf16_t)a.z;  o[3] = (bf16_t)a.w;
                o[4] = (bf16_t)bb.x; o[5] = (bf16_t)bb.y;
                o[6] = (bf16_t)bb.z; o[7] = (bf16_t)bb.w;
                *(bf16x8*)(w2b + (size_t)r * 4096 + col) = o;
            }
        } else {
#pragma unroll
            for (int k = 0; k < 4; ++k) {
                const int ii = c0 + k * 256;
                const int r = ii >> 9;
                const int col = (ii & 511) << 3;
                const int cc = col >> 9;
                const int code = idx2[cc * 1024 + r];
                *(bf16x8*)(w2b + (size_t)r * 4096 + col) =
                    *(const bf16x8*)((const bf16_t*)cb2 + (size_t)(cc * 256 + code) * 512 + (col & 511));
            }
        }
    }

    if (wb == 511) {
        for (int g = t; g < 640; g += 256) {
#pragma unroll
            for (int j = 0; j < 8; ++j) {
                const int e = g * 8 + j;
                const void* src = (e < 4096) ? b1 : b2;
                const int k = (e < 4096) ? e : e - 4096;
                const float v = f32 ? ((const float*)src)[k]
                                    : (float)(((const bf16_t*)src)[k]);
                if (e < 4096) b1f[k] = v; else b2f[k] = v;
            }
        }
    }
}

// ---------------- GEMM 128^2 (proven: 87.5us / MfmaUtil 35% at healthy clocks)
template <bool XCDSW, bool GELU, bool DYNOUT>
__global__ __launch_bounds__(256, 2)
void gemm_bt(const bf16_t* __restrict__ A, const bf16_t* __restrict__ Bw,
             const float* __restrict__ bias,
             bf16_t* __restrict__ obf, float* __restrict__ of32,
             int M, int N, int K, const int* __restrict__ flag) {
    __shared__ __attribute__((aligned(16))) bf16_t sA[128 * 64];
    __shared__ __attribute__((aligned(16))) bf16_t sB[128 * 64];

    const int tid = threadIdx.x;

    int bm, bn;
    if (XCDSW) {
        const int l = blockIdx.y * gridDim.x + blockIdx.x;
        const int xcd = l & 7;
        const int i = l >> 3;
        const int per = gridDim.y >> 3;
        bm = (xcd * per + (i % per)) << 7;
        bn = (i / per) << 7;
    } else {
        bm = blockIdx.y << 7;
        bn = blockIdx.x << 7;
    }

    const int row0 = tid >> 3;
    const int kc0 = ((tid & 7) - row0) & 7;
    const bf16_t* gA = A + (size_t)(bm + row0) * K + kc0 * 8;
    const bf16_t* gB = Bw + (size_t)(bn + row0) * K + kc0 * 8;
    bf16_t* lA = sA + tid * 8;
    bf16_t* lB = sB + tid * 8;
    const size_t pskip = (size_t)32 * K;

    const int lane = tid & 63;
    const int wave = tid >> 6;
    const int quad = lane >> 4;
    const int lr = lane & 15;
    const int wm = (wave & 1) << 6;
    const int wn = (wave >> 1) << 6;

    const int arow = wm + lr;
    const int brow = wn + lr;
    const bf16x8* pA0 = (const bf16x8*)(sA + arow * 64 + ((quad + arow) & 7) * 8);
    const bf16x8* pA1 = (const bf16x8*)(sA + arow * 64 + ((quad + 4 + arow) & 7) * 8);
    const bf16x8* pB0 = (const bf16x8*)(sB + brow * 64 + ((quad + brow) & 7) * 8);
    const bf16x8* pB1 = (const bf16x8*)(sB + brow * 64 + ((quad + 4 + brow) & 7) * 8);

    f32x4 acc[4][4] = {};

    for (int k0 = 0; k0 < K; k0 += 64) {
#pragma unroll
        for (int p = 0; p < 4; ++p) g2l16(gA + p * pskip + k0, lA + p * 2048);
#pragma unroll
        for (int p = 0; p < 4; ++p) g2l16(gB + p * pskip + k0, lB + p * 2048);
        __syncthreads();

        bf16x8 af[4], bf[4];
#pragma unroll
        for (int f = 0; f < 4; ++f) { af[f] = pA0[f * 128]; bf[f] = pB0[f * 128]; }
#pragma unroll
        for (int mi = 0; mi < 4; ++mi)
#pragma unroll
            for (int ni = 0; ni < 4; ++ni)
                acc[mi][ni] = __builtin_amdgcn_mfma_f32_16x16x32_bf16(
                    af[mi], bf[ni], acc[mi][ni], 0, 0, 0);
#pragma unroll
        for (int f = 0; f < 4; ++f) { af[f] = pA1[f * 128]; bf[f] = pB1[f * 128]; }
#pragma unroll
        for (int mi = 0; mi < 4; ++mi)
#pragma unroll
            for (int ni = 0; ni < 4; ++ni)
                acc[mi][ni] = __builtin_amdgcn_mfma_f32_16x16x32_bf16(
                    af[mi], bf[ni], acc[mi][ni], 0, 0, 0);
        __syncthreads();
    }

    const int outf32 = DYNOUT ? *flag : 0;
#pragma unroll
    for (int mi = 0; mi < 4; ++mi) {
#pragma unroll
        for (int ni = 0; ni < 4; ++ni) {
            const int n = bn + wn + ni * 16 + lr;
            const float bs = bias[n];
            f32x4 v = acc[mi][ni];
#pragma unroll
            for (int r = 0; r < 4; ++r) {
                const int m = bm + wm + mi * 16 + quad * 4 + r;
                float val = v[r] + bs;
                if (GELU) val = 0.5f * val * (1.0f + erff(val * 0.70710678118654752f));
                const size_t o = (size_t)m * N + n;
                if (DYNOUT) {
                    if (outf32) of32[o] = val;
                    else        obf[o] = (bf16_t)val;
                } else {
                    obf[o] = (bf16_t)val;
                }
            }
        }
    }
}

// ---------------- launch ----------------
extern "C" void kernel_launch(void* const* d_in, const int* in_sizes, int n_in,
                              void* d_out, int out_size, void* d_ws, size_t ws_size,
                              hipStream_t stream) {
    const void* x   = d_in[0];
    const void* cb1 = d_in[1];
    const int*  idx1 = (const int*)d_in[2];
    const void* b1  = d_in[3];
    const void* cb2 = d_in[4];
    const int*  idx2 = (const int*)d_in[5];
    const void* b2  = d_in[6];

    const int D = 1024, H = 4096;
    const int M = in_sizes[0] / D;     // 8192

    char* ws = (char*)d_ws;
    bf16_t* xb  = (bf16_t*)ws;                                   // M*D bf16 (16 MB)
    bf16_t* w1b = (bf16_t*)(ws + (size_t)M * D * 2);             // H*D bf16 (8 MB)
    bf16_t* hb  = (bf16_t*)((char*)w1b + (size_t)H * D * 2);     // M*H bf16 (64 MB)
    bf16_t* w2b = (bf16_t*)((char*)hb + (size_t)M * H * 2);      // D*H bf16 (8 MB)
    float*  b1f = (float*)((char*)w2b + (size_t)D * H * 2);      // H f32
    float*  b2f = b1f + H;                                       // D f32
    int*    flag = (int*)(b2f + D);

    // region-partitioned prep: M/8 x-blocks + 512 W1-blocks + 512 W2-blocks
    prep_all<<<(M >> 3) + 1024, 256, 0, stream>>>(x, cb1, idx1, b1, cb2, idx2, b2,
                                                  xb, w1b, w2b, b1f, b2f, flag, M);

    // GEMM1: proven 128^2 structure
    dim3 g1(H / 128, M / 128);   // (32, 64)
    gemm_bt<false, true, false><<<g1, 256, 0, stream>>>(xb, w1b, b1f, hb, nullptr, M, H, D, flag);

    // GEMM2: 128^2 + XCD swizzle (identical inner structure = in-run clock control)
    dim3 g2(D / 128, M / 128);   // (8, 64)
    gemm_bt<true, false, true><<<g2, 256, 0, stream>>>(hb, w2b, b2f,
        (bf16_t*)d_out, (float*)d_out, M, D, H, flag);
}